// Round 3
// baseline (393.463 us; speedup 1.0000x reference)
//
#include <hip/hip_runtime.h>
#include <hip/hip_bf16.h>
#include <hip/hip_fp16.h>

// ---------- types ----------
typedef __attribute__((ext_vector_type(8))) short    bf16x8;  // 8 bf16 MFMA A/B frag
typedef __attribute__((ext_vector_type(4))) float    f32x4;   // MFMA C/D frag
typedef __attribute__((ext_vector_type(4))) _Float16 f16x4;   // 16x16x16 f16 frag
typedef __attribute__((ext_vector_type(2))) __fp16   fp16x2_raw;  // cvt_pkrtz return type

typedef const void __attribute__((address_space(1))) gvoid_t;
typedef void __attribute__((address_space(3)))       lvoid_t;

static __device__ __forceinline__ void gload_lds16(const void* g, void* l) {
    __builtin_amdgcn_global_load_lds((gvoid_t*)g, (lvoid_t*)l, 16, 0, 0);
}

static __device__ __forceinline__ short bfbits(float f) {
    union { __hip_bfloat16 h; short s; } u;
    u.h = __float2bfloat16(f);
    return u.s;
}

// ---------- f32 -> bf16 convert ----------
__global__ __launch_bounds__(256) void cvt_bf16_kernel(const float* __restrict__ src,
                                                       __hip_bfloat16* __restrict__ dst, int n8) {
    int t = blockIdx.x * 256 + threadIdx.x;
    if (t >= n8) return;
    float4 a = ((const float4*)src)[2 * t];
    float4 b = ((const float4*)src)[2 * t + 1];
    bf16x8 o;
    o[0] = bfbits(a.x); o[1] = bfbits(a.y); o[2] = bfbits(a.z); o[3] = bfbits(a.w);
    o[4] = bfbits(b.x); o[5] = bfbits(b.y); o[6] = bfbits(b.z); o[7] = bfbits(b.w);
    ((bf16x8*)dst)[t] = o;
}

// ---------- f32 [K][N] -> bf16 [Npad][K] transpose-convert (zero pad n>=N) ----------
__global__ __launch_bounds__(256) void transpose_cvt(const float* __restrict__ src,
                                                     __hip_bfloat16* __restrict__ dst,
                                                     int K, int N, int Npad) {
    __shared__ __hip_bfloat16 tile[64][72];
    const int kb = blockIdx.x * 64;
    const int nb = blockIdx.y * 64;
    const int c  = threadIdx.x & 63;
    const int r0 = threadIdx.x >> 6;
    if (nb < N) {
#pragma unroll
        for (int i = 0; i < 16; ++i) {
            int r = r0 + i * 4;
            tile[r][c] = __float2bfloat16(src[(size_t)(kb + r) * N + nb + c]);
        }
        __syncthreads();
#pragma unroll
        for (int i = 0; i < 16; ++i) {
            int r = r0 + i * 4;
            dst[(size_t)(nb + r) * K + kb + c] = tile[c][r];
        }
    } else {
        __hip_bfloat16 z = __float2bfloat16(0.0f);
#pragma unroll
        for (int i = 0; i < 16; ++i) {
            int r = r0 + i * 4;
            dst[(size_t)(nb + r) * K + kb + c] = z;
        }
    }
}

__global__ void pad_bias_kernel(const float* __restrict__ b, float* __restrict__ out, int n, int npad) {
    int t = blockIdx.x * blockDim.x + threadIdx.x;
    if (t < npad) out[t] = (t < n) ? b[t] : 0.0f;
}

// ---------- f16 [rows][cols] -> f16 [cols][rows] transpose ----------
__global__ __launch_bounds__(256) void transpose_f16(const _Float16* __restrict__ src,
                                                     _Float16* __restrict__ dst,
                                                     int rows, int cols) {
    __shared__ _Float16 tile[64][72];
    const int cb = blockIdx.x * 64;
    const int rb = blockIdx.y * 64;
    const int c4 = (threadIdx.x & 15) * 4;
    const int rl = threadIdx.x >> 4;  // 0..15
#pragma unroll
    for (int i = 0; i < 4; ++i) {
        int row = rl + i * 16;
        *(f16x4*)&tile[row][c4] = *(const f16x4*)&src[(size_t)(rb + row) * cols + cb + c4];
    }
    __syncthreads();
#pragma unroll
    for (int i = 0; i < 4; ++i) {
        int orow = rl + i * 16;  // col index in src
        f16x4 v;
#pragma unroll
        for (int j = 0; j < 4; ++j) v[j] = tile[c4 + j][orow];
        *(f16x4*)&dst[(size_t)(cb + orow) * rows + rb + c4] = v;
    }
}

// ---------- GEMM: C[M][N] = A[M][K] @ Bt[N][K]^T, 64x128 tile, BK=32 ----------
// OUTMODE: 0 = bf16, 1 = f32, 2 = f16
template <int OUTMODE>
__global__ __launch_bounds__(256) void gemm64(const __hip_bfloat16* __restrict__ A,
                                              const __hip_bfloat16* __restrict__ Bt,
                                              const float* __restrict__ bias,
                                              void* __restrict__ Cout,
                                              int M, int N, int K,
                                              int lda, int ldb, int ldc, float outscale) {
    __shared__ __align__(16) __hip_bfloat16 sA[64 * 32];
    __shared__ __align__(16) __hip_bfloat16 sB[128 * 32];
    const int tid  = threadIdx.x;
    const int wid  = tid >> 6;
    const int lane = tid & 63;
    const int lr   = lane & 15;
    const int lg   = lane >> 4;
    const int mb   = blockIdx.y * 64;
    const int nb   = blockIdx.x * 128;
    const int wr   = (wid >> 1) * 32;
    const int wc   = (wid & 1) * 64;

    f32x4 acc[2][4] = {};

    for (int k0 = 0; k0 < K; k0 += 32) {
        {   // A tile 64x32: 4 chunks of 512 elems (one per wave)
            int e   = wid * 512 + lane * 8;
            int row = e >> 5, col = e & 31;
            gload_lds16(A + (size_t)(mb + row) * lda + (k0 + col), &sA[wid * 512]);
        }
#pragma unroll
        for (int j = 0; j < 2; ++j) {  // B tile 128x32: 8 chunks, 2 per wave
            int cb  = wid * 2 + j;
            int e   = cb * 512 + lane * 8;
            int row = e >> 5, col = e & 31;
            gload_lds16(Bt + (size_t)(nb + row) * ldb + (k0 + col), &sB[cb * 512]);
        }
        asm volatile("s_waitcnt vmcnt(0)" ::: "memory");
        __syncthreads();
        bf16x8 af[2], bfr[4];
#pragma unroll
        for (int m = 0; m < 2; ++m)
            af[m] = *(const bf16x8*)&sA[(wr + m * 16 + lr) * 32 + lg * 8];
#pragma unroll
        for (int n = 0; n < 4; ++n)
            bfr[n] = *(const bf16x8*)&sB[(wc + n * 16 + lr) * 32 + lg * 8];
#pragma unroll
        for (int m = 0; m < 2; ++m)
#pragma unroll
            for (int n = 0; n < 4; ++n)
                acc[m][n] = __builtin_amdgcn_mfma_f32_16x16x32_bf16(af[m], bfr[n], acc[m][n], 0, 0, 0);
        __syncthreads();
    }

#pragma unroll
    for (int n = 0; n < 4; ++n) {
        int col  = nb + wc + n * 16 + lr;
        float bv = bias ? bias[col] : 0.0f;
#pragma unroll
        for (int m = 0; m < 2; ++m) {
#pragma unroll
            for (int r = 0; r < 4; ++r) {
                int row    = mb + wr + m * 16 + lg * 4 + r;
                float val  = (acc[m][n][r] + bv) * outscale;
                size_t idx = (size_t)row * ldc + col;
                if constexpr (OUTMODE == 1)      ((float*)Cout)[idx] = val;
                else if constexpr (OUTMODE == 2) ((_Float16*)Cout)[idx] = (_Float16)val;
                else                             ((__hip_bfloat16*)Cout)[idx] = __float2bfloat16(val);
            }
        }
    }
}

// ---------- RoPE (faithful quirk: cos_pos=sin(pe), sin_pos=cos(pe)), in-place ----------
__global__ __launch_bounds__(256) void rope_kernel(__hip_bfloat16* __restrict__ x,
                                                   int rows, int heads, int rowstride, int S) {
    int t = blockIdx.x * 256 + threadIdx.x;
    if (t >= rows * heads * 32) return;
    int i   = t & 31;
    int hh  = (t >> 5) % heads;
    int row = t / (heads * 32);
    int pos = row % S;
    float theta = __expf(-0.28782313662425572f * (float)i);
    float pe = (float)pos * theta;
    float sp, cp;
    sincosf(pe, &sp, &cp);
    size_t idx = (size_t)row * rowstride + hh * 64 + 2 * i;
    float x0 = __bfloat162float(x[idx]);
    float x1 = __bfloat162float(x[idx + 1]);
    x[idx]     = __float2bfloat16(x0 * sp - x1 * cp);
    x[idx + 1] = __float2bfloat16(x1 * sp + x0 * cp);
}

// ---------- Flash attention v2 ----------
// grid (S/64, 16, B), 128 thr (2 waves), wave owns 32 q rows (2 groups of 16).
// KV tile = 64. Scores arrive pre-scaled by log2e/16 (folded into uq/qr GEMM),
// softmax uses exp2 directly. V pre-transposed [1024][R] f16 -> 8B frag loads.
__global__ __launch_bounds__(128, 2) void attn_kernel(const __hip_bfloat16* __restrict__ qcat,
                                                      const __hip_bfloat16* __restrict__ ktc,
                                                      const __hip_bfloat16* __restrict__ kr,
                                                      const _Float16* __restrict__ vtcT,
                                                      __hip_bfloat16* __restrict__ outp,
                                                      int S, int R) {
    const int tid  = threadIdx.x;
    const int wid  = tid >> 6;
    const int lane = tid & 63;
    const int lr   = lane & 15;
    const int lg   = lane >> 4;
    const int h    = blockIdx.y;
    const int b    = blockIdx.z;
    const size_t base = (size_t)b * S;
    const int qb   = blockIdx.x * 64 + wid * 32;

    bf16x8 qf[2][4];
#pragma unroll
    for (int g = 0; g < 2; ++g) {
        size_t row = base + qb + g * 16 + lr;
        const __hip_bfloat16* pq = qcat + row * 2048 + h * 64;
        qf[g][0] = *(const bf16x8*)(pq + lg * 8);
        qf[g][1] = *(const bf16x8*)(pq + 32 + lg * 8);
        qf[g][2] = *(const bf16x8*)(pq + 1024 + lg * 8);
        qf[g][3] = *(const bf16x8*)(pq + 1024 + 32 + lg * 8);
    }

    f32x4 oacc[2][4] = {};
    float mrun[2] = {-1.0e30f, -1.0e30f};
    float lrun[2] = {0.0f, 0.0f};

    for (int kt = 0; kt < S; kt += 64) {
        bf16x8 kf[4][4];
#pragma unroll
        for (int st = 0; st < 4; ++st) {
            size_t row = base + kt + st * 16 + lr;
            const __hip_bfloat16* pk  = ktc + row * 1024 + h * 64;
            const __hip_bfloat16* pkr = kr + row * 640;  // roped K, cols 0..63
            kf[st][0] = *(const bf16x8*)(pk + lg * 8);
            kf[st][1] = *(const bf16x8*)(pk + 32 + lg * 8);
            kf[st][2] = *(const bf16x8*)(pkr + lg * 8);
            kf[st][3] = *(const bf16x8*)(pkr + 32 + lg * 8);
        }
        f16x4 vf[4][4];  // [subtile][vt]
#pragma unroll
        for (int st = 0; st < 4; ++st)
#pragma unroll
            for (int vt = 0; vt < 4; ++vt)
                vf[st][vt] = *(const f16x4*)&vtcT[(size_t)(h * 64 + vt * 16 + lr) * R +
                                                  base + kt + st * 16 + lg * 4];
#pragma unroll
        for (int g = 0; g < 2; ++g) {
            f32x4 sacc[4] = {};
#pragma unroll
            for (int st = 0; st < 4; ++st)
#pragma unroll
                for (int c = 0; c < 4; ++c)
                    sacc[st] = __builtin_amdgcn_mfma_f32_16x16x32_bf16(kf[st][c], qf[g][c], sacc[st], 0, 0, 0);
            float tmax = -1.0e30f;
#pragma unroll
            for (int st = 0; st < 4; ++st)
                tmax = fmaxf(tmax, fmaxf(fmaxf(sacc[st][0], sacc[st][1]),
                                         fmaxf(sacc[st][2], sacc[st][3])));
            tmax = fmaxf(tmax, __shfl_xor(tmax, 16));
            tmax = fmaxf(tmax, __shfl_xor(tmax, 32));
            if (__any(tmax > mrun[g] + 11.0f)) {  // defer-max (T13), exp2 domain
                float mnew = fmaxf(mrun[g], tmax);
                float rf   = __builtin_exp2f(mrun[g] - mnew);
                mrun[g]    = mnew;
                lrun[g] *= rf;
#pragma unroll
                for (int vt = 0; vt < 4; ++vt) {
                    oacc[g][vt][0] *= rf; oacc[g][vt][1] *= rf;
                    oacc[g][vt][2] *= rf; oacc[g][vt][3] *= rf;
                }
            }
            float p[4][4];
            float ts = 0.0f;
#pragma unroll
            for (int st = 0; st < 4; ++st) {
#pragma unroll
                for (int r = 0; r < 4; ++r) {
                    p[st][r] = __builtin_exp2f(sacc[st][r] - mrun[g]);
                    ts += p[st][r];
                }
            }
            ts += __shfl_xor(ts, 16);
            ts += __shfl_xor(ts, 32);
            lrun[g] += ts;
#pragma unroll
            for (int st = 0; st < 4; ++st) {
                union { fp16x2_raw h2[2]; f16x4 v; } pu;
                pu.h2[0] = __builtin_amdgcn_cvt_pkrtz(p[st][0], p[st][1]);
                pu.h2[1] = __builtin_amdgcn_cvt_pkrtz(p[st][2], p[st][3]);
#pragma unroll
                for (int vt = 0; vt < 4; ++vt)
                    oacc[g][vt] = __builtin_amdgcn_mfma_f32_16x16x16f16(vf[st][vt], pu.v, oacc[g][vt], 0, 0, 0);
            }
        }
    }
#pragma unroll
    for (int g = 0; g < 2; ++g) {
        float inv = 1.0f / lrun[g];
        size_t rowoff = (base + qb + g * 16 + lr) << 10;
#pragma unroll
        for (int vt = 0; vt < 4; ++vt)
#pragma unroll
            for (int r = 0; r < 4; ++r)
                outp[rowoff + h * 64 + vt * 16 + lg * 4 + r] =
                    __float2bfloat16(oacc[g][vt][r] * inv);
    }
}

// ---------- launch ----------
extern "C" void kernel_launch(void* const* d_in, const int* in_sizes, int n_in,
                              void* d_out, int out_size, void* d_ws, size_t ws_size,
                              hipStream_t stream) {
    const float* query = (const float*)d_in[0];
    const float* key   = (const float*)d_in[1];
    const float* w_dkv = (const float*)d_in[3];
    const float* b_dkv = (const float*)d_in[4];
    const float* w_uk  = (const float*)d_in[5];
    const float* b_uk  = (const float*)d_in[6];
    const float* w_uv  = (const float*)d_in[7];
    const float* b_uv  = (const float*)d_in[8];
    const float* w_dq  = (const float*)d_in[9];
    const float* b_dq  = (const float*)d_in[10];
    const float* w_uq  = (const float*)d_in[11];
    const float* b_uq  = (const float*)d_in[12];
    const float* w_qr  = (const float*)d_in[13];
    const float* b_qr  = (const float*)d_in[14];
    const float* w_kr  = (const float*)d_in[15];
    const float* b_kr  = (const float*)d_in[16];
    const float* w_fc  = (const float*)d_in[17];
    const float* b_fc  = (const float*)d_in[18];

    const int B = 2;
    const int R = in_sizes[0] / 1024;  // B*S = 4096
    const int S = R / B;               // 2048
    const float QSCALE = 1.4426950408889634f / 16.0f;  // log2e / (sqrt(64)+sqrt(64))

    char* ws = (char*)d_ws;
    size_t off = 0;
    auto alloc = [&](size_t bytes) -> char* {
        char* p = ws + off;
        off += (bytes + 255) & ~(size_t)255;
        return p;
    };

    __hip_bfloat16* q_bf  = (__hip_bfloat16*)alloc((size_t)R * 1024 * 2);
    __hip_bfloat16* k_bf  = (__hip_bfloat16*)alloc((size_t)R * 1024 * 2);
    __hip_bfloat16* wcat1 = (__hip_bfloat16*)alloc(640 * 1024 * 2);   // [dkv(512); kr pad(128)] rows x K=1024
    __hip_bfloat16* wdq_t = (__hip_bfloat16*)alloc(512 * 1024 * 2);
    __hip_bfloat16* wuk_t = (__hip_bfloat16*)alloc(1024 * 512 * 2);
    __hip_bfloat16* wuv_t = (__hip_bfloat16*)alloc(1024 * 512 * 2);
    __hip_bfloat16* wcat2 = (__hip_bfloat16*)alloc(2048 * 512 * 2);   // [uq(1024); qr(1024)] rows x K=512
    __hip_bfloat16* wfc_t = (__hip_bfloat16*)alloc(1024 * 1024 * 2);
    float*          bcat1 = (float*)alloc(640 * 4);
    float*          bcat2 = (float*)alloc(2048 * 4);
    __hip_bfloat16* ckkr  = (__hip_bfloat16*)alloc((size_t)R * 640 * 2);   // [c_kv(512) | krope(128)]
    __hip_bfloat16* c_q   = (__hip_bfloat16*)alloc((size_t)R * 512 * 2);
    __hip_bfloat16* ktc   = (__hip_bfloat16*)alloc((size_t)R * 1024 * 2);
    _Float16*       vtcT  = (_Float16*)alloc((size_t)R * 1024 * 2);        // [1024][R]
    __hip_bfloat16* qcat  = (__hip_bfloat16*)alloc((size_t)R * 2048 * 2);  // [qtc(1024) | qrope(1024)]
    _Float16*       vtc   = (_Float16*)qcat;  // alias: row-major V dead before qcat is written
    __hip_bfloat16* attn_out = q_bf;          // alias: q_bf dead after dq GEMM

    // input converts
    cvt_bf16_kernel<<<dim3(R * 1024 / 8 / 256), 256, 0, stream>>>(query, q_bf, R * 1024 / 8);
    cvt_bf16_kernel<<<dim3(R * 1024 / 8 / 256), 256, 0, stream>>>(key, k_bf, R * 1024 / 8);
    // weight transposes to [N][K] bf16 (+ fused concats)
    transpose_cvt<<<dim3(16, 8),  256, 0, stream>>>(w_dkv, wcat1, 1024, 512, 512);
    transpose_cvt<<<dim3(16, 2),  256, 0, stream>>>(w_kr,  wcat1 + 512 * 1024, 1024, 64, 128);
    transpose_cvt<<<dim3(16, 8),  256, 0, stream>>>(w_dq,  wdq_t, 1024, 512, 512);
    transpose_cvt<<<dim3(8, 16),  256, 0, stream>>>(w_uk,  wuk_t, 512, 1024, 1024);
    transpose_cvt<<<dim3(8, 16),  256, 0, stream>>>(w_uv,  wuv_t, 512, 1024, 1024);
    transpose_cvt<<<dim3(8, 16),  256, 0, stream>>>(w_uq,  wcat2, 512, 1024, 1024);
    transpose_cvt<<<dim3(8, 16),  256, 0, stream>>>(w_qr,  wcat2 + 1024 * 512, 512, 1024, 1024);
    transpose_cvt<<<dim3(16, 16), 256, 0, stream>>>(w_fc,  wfc_t, 1024, 1024, 1024);
    pad_bias_kernel<<<2, 256, 0, stream>>>(b_dkv, bcat1, 512, 512);
    pad_bias_kernel<<<1, 128, 0, stream>>>(b_kr, bcat1 + 512, 64, 128);
    pad_bias_kernel<<<4, 256, 0, stream>>>(b_uq, bcat2, 1024, 1024);
    pad_bias_kernel<<<4, 256, 0, stream>>>(b_qr, bcat2 + 1024, 1024, 1024);

    // projection GEMMs (64x128 tiles)
    gemm64<0><<<dim3(5, R / 64),  256, 0, stream>>>(k_bf, wcat1, bcat1, ckkr, R, 640, 1024, 1024, 1024, 640, 1.0f);
    gemm64<0><<<dim3(4, R / 64),  256, 0, stream>>>(q_bf, wdq_t, b_dq, c_q, R, 512, 1024, 1024, 1024, 512, 1.0f);
    gemm64<0><<<dim3(8, R / 64),  256, 0, stream>>>(ckkr, wuk_t, b_uk, ktc, R, 1024, 512, 640, 512, 1024, 1.0f);
    gemm64<2><<<dim3(8, R / 64),  256, 0, stream>>>(ckkr, wuv_t, b_uv, vtc, R, 1024, 512, 640, 512, 1024, 1.0f);
    transpose_f16<<<dim3(16, R / 64), 256, 0, stream>>>(vtc, vtcT, R, 1024);
    gemm64<0><<<dim3(16, R / 64), 256, 0, stream>>>(c_q, wcat2, bcat2, qcat, R, 2048, 512, 512, 512, 2048, QSCALE);

    // RoPE (in-place; qrope at qcat col 1024, krope at ckkr col 512)
    rope_kernel<<<dim3((R * 16 * 32 + 255) / 256), 256, 0, stream>>>(qcat + 1024, R, 16, 2048, S);
    rope_kernel<<<dim3((R * 32 + 255) / 256), 256, 0, stream>>>(ckkr + 512, R, 1, 640, S);

    // attention
    attn_kernel<<<dim3(S / 64, 16, B), 128, 0, stream>>>(qcat, ktc, ckkr + 512, vtcT, attn_out, S, R);

    // output projection (f32 to d_out)
    gemm64<1><<<dim3(8, R / 64), 256, 0, stream>>>(attn_out, wfc_t, b_fc, (float*)d_out, R, 1024, 1024, 1024, 1024, 1024, 1.0f);
}

// Round 4
// 254.254 us; speedup vs baseline: 1.5475x; 1.5475x over previous
//
#include <hip/hip_runtime.h>
#include <hip/hip_bf16.h>
#include <hip/hip_fp16.h>

// ---------- types ----------
typedef __attribute__((ext_vector_type(8))) short    bf16x8;  // 8 bf16 MFMA A/B frag
typedef __attribute__((ext_vector_type(4))) float    f32x4;   // MFMA C/D frag
typedef __attribute__((ext_vector_type(4))) _Float16 f16x4;   // 16x16x16 f16 frag
typedef __attribute__((ext_vector_type(2))) __fp16   fp16x2_raw;  // cvt_pkrtz return type

typedef const void __attribute__((address_space(1))) gvoid_t;
typedef void __attribute__((address_space(3)))       lvoid_t;

static __device__ __forceinline__ void gload_lds16(const void* g, void* l) {
    // LDS dest = wave-uniform base + lane*16B; global src is per-lane.
    __builtin_amdgcn_global_load_lds((gvoid_t*)g, (lvoid_t*)l, 16, 0, 0);
}

static __device__ __forceinline__ short bfbits(float f) {
    union { __hip_bfloat16 h; short s; } u;
    u.h = __float2bfloat16(f);
    return u.s;
}

// ---------- f32 -> bf16 convert ----------
__global__ __launch_bounds__(256) void cvt_bf16_kernel(const float* __restrict__ src,
                                                       __hip_bfloat16* __restrict__ dst, int n8) {
    int t = blockIdx.x * 256 + threadIdx.x;
    if (t >= n8) return;
    float4 a = ((const float4*)src)[2 * t];
    float4 b = ((const float4*)src)[2 * t + 1];
    bf16x8 o;
    o[0] = bfbits(a.x); o[1] = bfbits(a.y); o[2] = bfbits(a.z); o[3] = bfbits(a.w);
    o[4] = bfbits(b.x); o[5] = bfbits(b.y); o[6] = bfbits(b.z); o[7] = bfbits(b.w);
    ((bf16x8*)dst)[t] = o;
}

// ---------- f32 [K][N] -> bf16 [Npad][K] transpose-convert (zero pad n>=N) ----------
__global__ __launch_bounds__(256) void transpose_cvt(const float* __restrict__ src,
                                                     __hip_bfloat16* __restrict__ dst,
                                                     int K, int N, int Npad) {
    __shared__ __hip_bfloat16 tile[64][72];
    const int kb = blockIdx.x * 64;
    const int nb = blockIdx.y * 64;
    const int c  = threadIdx.x & 63;
    const int r0 = threadIdx.x >> 6;
    if (nb < N) {
#pragma unroll
        for (int i = 0; i < 16; ++i) {
            int r = r0 + i * 4;
            tile[r][c] = __float2bfloat16(src[(size_t)(kb + r) * N + nb + c]);
        }
        __syncthreads();
#pragma unroll
        for (int i = 0; i < 16; ++i) {
            int r = r0 + i * 4;
            dst[(size_t)(nb + r) * K + kb + c] = tile[c][r];
        }
    } else {
        __hip_bfloat16 z = __float2bfloat16(0.0f);
#pragma unroll
        for (int i = 0; i < 16; ++i) {
            int r = r0 + i * 4;
            dst[(size_t)(nb + r) * K + kb + c] = z;
        }
    }
}

__global__ void pad_bias_kernel(const float* __restrict__ b, float* __restrict__ out, int n, int npad) {
    int t = blockIdx.x * blockDim.x + threadIdx.x;
    if (t < npad) out[t] = (t < n) ? b[t] : 0.0f;
}

// ---------- f16 [rows][cols] -> f16 [cols][rows] transpose ----------
__global__ __launch_bounds__(256) void transpose_f16(const _Float16* __restrict__ src,
                                                     _Float16* __restrict__ dst,
                                                     int rows, int cols) {
    __shared__ _Float16 tile[64][72];
    const int cb = blockIdx.x * 64;
    const int rb = blockIdx.y * 64;
    const int c4 = (threadIdx.x & 15) * 4;
    const int rl = threadIdx.x >> 4;  // 0..15
#pragma unroll
    for (int i = 0; i < 4; ++i) {
        int row = rl + i * 16;
        *(f16x4*)&tile[row][c4] = *(const f16x4*)&src[(size_t)(rb + row) * cols + cb + c4];
    }
    __syncthreads();
#pragma unroll
    for (int i = 0; i < 4; ++i) {
        int orow = rl + i * 16;  // col index in src
        f16x4 v;
#pragma unroll
        for (int j = 0; j < 4; ++j) v[j] = tile[c4 + j][orow];
        *(f16x4*)&dst[(size_t)(cb + orow) * rows + rb + c4] = v;
    }
}

// ---------- GEMM: C[M][N] = A[M][K] @ Bt[N][K]^T, 64x128 tile, BK=32 ----------
// OUTMODE: 0 = bf16, 1 = f32, 2 = f16
template <int OUTMODE>
__global__ __launch_bounds__(256) void gemm64(const __hip_bfloat16* __restrict__ A,
                                              const __hip_bfloat16* __restrict__ Bt,
                                              const float* __restrict__ bias,
                                              void* __restrict__ Cout,
                                              int M, int N, int K,
                                              int lda, int ldb, int ldc, float outscale) {
    __shared__ __align__(16) __hip_bfloat16 sA[64 * 32];
    __shared__ __align__(16) __hip_bfloat16 sB[128 * 32];
    const int tid  = threadIdx.x;
    const int wid  = tid >> 6;
    const int lane = tid & 63;
    const int lr   = lane & 15;
    const int lg   = lane >> 4;
    const int mb   = blockIdx.y * 64;
    const int nb   = blockIdx.x * 128;
    const int wr   = (wid >> 1) * 32;
    const int wc   = (wid & 1) * 64;

    f32x4 acc[2][4] = {};

    for (int k0 = 0; k0 < K; k0 += 32) {
        {   // A tile 64x32: 4 chunks of 512 elems (one per wave)
            int e   = wid * 512 + lane * 8;
            int row = e >> 5, col = e & 31;
            gload_lds16(A + (size_t)(mb + row) * lda + (k0 + col), &sA[wid * 512]);
        }
#pragma unroll
        for (int j = 0; j < 2; ++j) {  // B tile 128x32: 8 chunks, 2 per wave
            int cb  = wid * 2 + j;
            int e   = cb * 512 + lane * 8;
            int row = e >> 5, col = e & 31;
            gload_lds16(Bt + (size_t)(nb + row) * ldb + (k0 + col), &sB[cb * 512]);
        }
        asm volatile("s_waitcnt vmcnt(0)" ::: "memory");
        __syncthreads();
        bf16x8 af[2], bfr[4];
#pragma unroll
        for (int m = 0; m < 2; ++m)
            af[m] = *(const bf16x8*)&sA[(wr + m * 16 + lr) * 32 + lg * 8];
#pragma unroll
        for (int n = 0; n < 4; ++n)
            bfr[n] = *(const bf16x8*)&sB[(wc + n * 16 + lr) * 32 + lg * 8];
#pragma unroll
        for (int m = 0; m < 2; ++m)
#pragma unroll
            for (int n = 0; n < 4; ++n)
                acc[m][n] = __builtin_amdgcn_mfma_f32_16x16x32_bf16(af[m], bfr[n], acc[m][n], 0, 0, 0);
        __syncthreads();
    }

#pragma unroll
    for (int n = 0; n < 4; ++n) {
        int col  = nb + wc + n * 16 + lr;
        float bv = bias ? bias[col] : 0.0f;
#pragma unroll
        for (int m = 0; m < 2; ++m) {
#pragma unroll
            for (int r = 0; r < 4; ++r) {
                int row    = mb + wr + m * 16 + lg * 4 + r;
                float val  = (acc[m][n][r] + bv) * outscale;
                size_t idx = (size_t)row * ldc + col;
                if constexpr (OUTMODE == 1)      ((float*)Cout)[idx] = val;
                else if constexpr (OUTMODE == 2) ((_Float16*)Cout)[idx] = (_Float16)val;
                else                             ((__hip_bfloat16*)Cout)[idx] = __float2bfloat16(val);
            }
        }
    }
}

// ---------- RoPE (faithful quirk: cos_pos=sin(pe), sin_pos=cos(pe)), in-place ----------
__global__ __launch_bounds__(256) void rope_kernel(__hip_bfloat16* __restrict__ x,
                                                   int rows, int heads, int rowstride, int S) {
    int t = blockIdx.x * 256 + threadIdx.x;
    if (t >= rows * heads * 32) return;
    int i   = t & 31;
    int hh  = (t >> 5) % heads;
    int row = t / (heads * 32);
    int pos = row % S;
    float theta = __expf(-0.28782313662425572f * (float)i);
    float pe = (float)pos * theta;
    float sp, cp;
    sincosf(pe, &sp, &cp);
    size_t idx = (size_t)row * rowstride + hh * 64 + 2 * i;
    float x0 = __bfloat162float(x[idx]);
    float x1 = __bfloat162float(x[idx + 1]);
    x[idx]     = __float2bfloat16(x0 * sp - x1 * cp);
    x[idx + 1] = __float2bfloat16(x1 * sp + x0 * cp);
}

// ---------- Flash attention v3: LDS-staged KV, double-buffered 2-phase ----------
// grid (S/128, 16, B), 256 thr (4 waves), wave owns 32 q rows (2 groups of 16).
// KV tile = 64 keys. Per tile the block cooperatively stages:
//   Kc tile [64 keys][128 dims] bf16 (cols 0..63 ktc, 64..127 rope-K) = 16 KB
//   Vt tile [64 dims][64 keys] f16 = 8 KB
// via global_load_lds (linear LDS dest, per-lane global src pre-swizzled:
// 16B slot s of row r holds global slot s^(r&7) -> conflict-free ds_reads).
// Scores pre-scaled by log2e/16 (folded into uq/qr GEMM) -> exp2 softmax.
__global__ __launch_bounds__(256) void attn_kernel(const __hip_bfloat16* __restrict__ qcat,
                                                   const __hip_bfloat16* __restrict__ ktc,
                                                   const __hip_bfloat16* __restrict__ kr,
                                                   const _Float16* __restrict__ vtcT,
                                                   __hip_bfloat16* __restrict__ outp,
                                                   int S, int R) {
    __shared__ __align__(16) char lds[2][24 * 1024];  // [K 16KB | V 8KB] x 2
    const int tid  = threadIdx.x;
    const int wid  = tid >> 6;
    const int lane = tid & 63;
    const int lr   = lane & 15;
    const int lg   = lane >> 4;
    const int h    = blockIdx.y;
    const int b    = blockIdx.z;
    const size_t base = (size_t)b * S;
    const int qb   = blockIdx.x * 128 + wid * 32;

    // ---- stage one 64-key tile into lds[bufi] ----
    auto stage = [&](int bufi, int kt) {
        char* bufK = lds[bufi];
        char* bufV = lds[bufi] + 16 * 1024;
        // K: 16 chunks of 1KB (4 rows x 256B); wave w does chunks 4w..4w+3
#pragma unroll
        for (int j = 0; j < 4; ++j) {
            int c   = wid * 4 + j;
            int rho = c * 4 + (lane >> 4);       // key-local row 0..63
            int u   = (lane & 15) ^ (rho & 7);   // global 16B slot (inverse swizzle)
            const __hip_bfloat16* src = (u < 8)
                ? ktc + (base + kt + rho) * 1024 + h * 64 + u * 8
                : kr  + (base + kt + rho) * 640 + (u & 7) * 8;
            gload_lds16(src, bufK + c * 1024);
        }
        // V^T: 8 chunks of 1KB (8 dim-rows x 128B); wave w does chunks 2w..2w+1
#pragma unroll
        for (int j = 0; j < 2; ++j) {
            int c   = wid * 2 + j;
            int rho = c * 8 + (lane >> 3);       // dim-local row 0..63
            int u   = (lane & 7) ^ (rho & 7);    // global 16B slot (keys u*8..u*8+7)
            gload_lds16(vtcT + (size_t)(h * 64 + rho) * R + base + kt + u * 8,
                        bufV + c * 1024);
        }
    };

    // ---- Q fragments (held in registers for the whole kernel) ----
    bf16x8 qf[2][4];
#pragma unroll
    for (int g = 0; g < 2; ++g) {
        size_t row = base + qb + g * 16 + lr;
        const __hip_bfloat16* pq = qcat + row * 2048 + h * 64;
        qf[g][0] = *(const bf16x8*)(pq + lg * 8);
        qf[g][1] = *(const bf16x8*)(pq + 32 + lg * 8);
        qf[g][2] = *(const bf16x8*)(pq + 1024 + lg * 8);
        qf[g][3] = *(const bf16x8*)(pq + 1024 + 32 + lg * 8);
    }

    f32x4 oacc[2][4] = {};
    float mrun[2] = {-1.0e30f, -1.0e30f};
    float lrun[2] = {0.0f, 0.0f};

    const int NT = S / 64;
    stage(0, 0);
    __syncthreads();  // vmcnt(0)+lgkmcnt(0)+barrier: tile 0 staged

    for (int t = 0; t < NT; ++t) {
        const int cur = t & 1;
        if (t + 1 < NT) stage(cur ^ 1, (t + 1) * 64);  // prefetch next tile

        const char* bufK = lds[cur];
        const char* bufV = lds[cur] + 16 * 1024;

        // QK^T for both q-groups: sacc[g][st], swapped operands (K as A)
        f32x4 sacc[2][4] = {};
#pragma unroll
        for (int st = 0; st < 4; ++st) {
            bf16x8 kf[4];
#pragma unroll
            for (int c = 0; c < 4; ++c)
                kf[c] = *(const bf16x8*)(bufK + (st * 16 + lr) * 256 +
                                         (((c * 4 + lg) ^ (lr & 7)) << 4));
#pragma unroll
            for (int g = 0; g < 2; ++g)
#pragma unroll
                for (int c = 0; c < 4; ++c)
                    sacc[g][st] = __builtin_amdgcn_mfma_f32_16x16x32_bf16(kf[c], qf[g][c], sacc[g][st], 0, 0, 0);
        }

        // V^T fragments (shared by both q-groups)
        f16x4 vf[4][4];  // [st][vt]
#pragma unroll
        for (int st = 0; st < 4; ++st)
#pragma unroll
            for (int vt = 0; vt < 4; ++vt)
                vf[st][vt] = *(const f16x4*)(bufV + (vt * 16 + lr) * 128 +
                                             (((st * 2 + (lg >> 1)) ^ (lr & 7)) << 4) + (lg & 1) * 8);

#pragma unroll
        for (int g = 0; g < 2; ++g) {
            float tmax = -1.0e30f;
#pragma unroll
            for (int st = 0; st < 4; ++st)
                tmax = fmaxf(tmax, fmaxf(fmaxf(sacc[g][st][0], sacc[g][st][1]),
                                         fmaxf(sacc[g][st][2], sacc[g][st][3])));
            tmax = fmaxf(tmax, __shfl_xor(tmax, 16));
            tmax = fmaxf(tmax, __shfl_xor(tmax, 32));
            if (__any(tmax > mrun[g] + 11.0f)) {  // defer-max (T13), exp2 domain
                float mnew = fmaxf(mrun[g], tmax);
                float rf   = __builtin_exp2f(mrun[g] - mnew);
                mrun[g]    = mnew;
                lrun[g] *= rf;
#pragma unroll
                for (int vt = 0; vt < 4; ++vt) {
                    oacc[g][vt][0] *= rf; oacc[g][vt][1] *= rf;
                    oacc[g][vt][2] *= rf; oacc[g][vt][3] *= rf;
                }
            }
            float p[4][4];
            float ts = 0.0f;
#pragma unroll
            for (int st = 0; st < 4; ++st)
#pragma unroll
                for (int r = 0; r < 4; ++r) {
                    p[st][r] = __builtin_exp2f(sacc[g][st][r] - mrun[g]);
                    ts += p[st][r];
                }
            ts += __shfl_xor(ts, 16);
            ts += __shfl_xor(ts, 32);
            lrun[g] += ts;
#pragma unroll
            for (int st = 0; st < 4; ++st) {
                union { fp16x2_raw h2[2]; f16x4 v; } pu;
                pu.h2[0] = __builtin_amdgcn_cvt_pkrtz(p[st][0], p[st][1]);
                pu.h2[1] = __builtin_amdgcn_cvt_pkrtz(p[st][2], p[st][3]);
#pragma unroll
                for (int vt = 0; vt < 4; ++vt)
                    oacc[g][vt] = __builtin_amdgcn_mfma_f32_16x16x16f16(vf[st][vt], pu.v, oacc[g][vt], 0, 0, 0);
            }
        }
        __syncthreads();  // drains this wave's staging loads + all waves' LDS reads
    }

#pragma unroll
    for (int g = 0; g < 2; ++g) {
        float inv = 1.0f / lrun[g];
        size_t rowoff = (base + qb + g * 16 + lr) << 10;
#pragma unroll
        for (int vt = 0; vt < 4; ++vt)
#pragma unroll
            for (int r = 0; r < 4; ++r)
                outp[rowoff + h * 64 + vt * 16 + lg * 4 + r] =
                    __float2bfloat16(oacc[g][vt][r] * inv);
    }
}

// ---------- launch ----------
extern "C" void kernel_launch(void* const* d_in, const int* in_sizes, int n_in,
                              void* d_out, int out_size, void* d_ws, size_t ws_size,
                              hipStream_t stream) {
    const float* query = (const float*)d_in[0];
    const float* key   = (const float*)d_in[1];
    const float* w_dkv = (const float*)d_in[3];
    const float* b_dkv = (const float*)d_in[4];
    const float* w_uk  = (const float*)d_in[5];
    const float* b_uk  = (const float*)d_in[6];
    const float* w_uv  = (const float*)d_in[7];
    const float* b_uv  = (const float*)d_in[8];
    const float* w_dq  = (const float*)d_in[9];
    const float* b_dq  = (const float*)d_in[10];
    const float* w_uq  = (const float*)d_in[11];
    const float* b_uq  = (const float*)d_in[12];
    const float* w_qr  = (const float*)d_in[13];
    const float* b_qr  = (const float*)d_in[14];
    const float* w_kr  = (const float*)d_in[15];
    const float* b_kr  = (const float*)d_in[16];
    const float* w_fc  = (const float*)d_in[17];
    const float* b_fc  = (const float*)d_in[18];

    const int B = 2;
    const int R = in_sizes[0] / 1024;  // B*S = 4096
    const int S = R / B;               // 2048
    const float QSCALE = 1.4426950408889634f / 16.0f;  // log2e / (sqrt(64)+sqrt(64))

    char* ws = (char*)d_ws;
    size_t off = 0;
    auto alloc = [&](size_t bytes) -> char* {
        char* p = ws + off;
        off += (bytes + 255) & ~(size_t)255;
        return p;
    };

    __hip_bfloat16* q_bf  = (__hip_bfloat16*)alloc((size_t)R * 1024 * 2);
    __hip_bfloat16* k_bf  = (__hip_bfloat16*)alloc((size_t)R * 1024 * 2);
    __hip_bfloat16* wcat1 = (__hip_bfloat16*)alloc(640 * 1024 * 2);   // [dkv(512); kr pad(128)] rows x K=1024
    __hip_bfloat16* wdq_t = (__hip_bfloat16*)alloc(512 * 1024 * 2);
    __hip_bfloat16* wuk_t = (__hip_bfloat16*)alloc(1024 * 512 * 2);
    __hip_bfloat16* wuv_t = (__hip_bfloat16*)alloc(1024 * 512 * 2);
    __hip_bfloat16* wcat2 = (__hip_bfloat16*)alloc(2048 * 512 * 2);   // [uq(1024); qr(1024)] rows x K=512
    __hip_bfloat16* wfc_t = (__hip_bfloat16*)alloc(1024 * 1024 * 2);
    float*          bcat1 = (float*)alloc(640 * 4);
    float*          bcat2 = (float*)alloc(2048 * 4);
    __hip_bfloat16* ckkr  = (__hip_bfloat16*)alloc((size_t)R * 640 * 2);   // [c_kv(512) | krope(128)]
    __hip_bfloat16* c_q   = (__hip_bfloat16*)alloc((size_t)R * 512 * 2);
    __hip_bfloat16* ktc   = (__hip_bfloat16*)alloc((size_t)R * 1024 * 2);
    _Float16*       vtcT  = (_Float16*)alloc((size_t)R * 1024 * 2);        // [1024][R]
    __hip_bfloat16* qcat  = (__hip_bfloat16*)alloc((size_t)R * 2048 * 2);  // [qtc(1024) | qrope(1024)]
    _Float16*       vtc   = (_Float16*)qcat;  // alias: row-major V dead before qcat is written
    __hip_bfloat16* attn_out = q_bf;          // alias: q_bf dead after dq GEMM

    // input converts
    cvt_bf16_kernel<<<dim3(R * 1024 / 8 / 256), 256, 0, stream>>>(query, q_bf, R * 1024 / 8);
    cvt_bf16_kernel<<<dim3(R * 1024 / 8 / 256), 256, 0, stream>>>(key, k_bf, R * 1024 / 8);
    // weight transposes to [N][K] bf16 (+ fused concats)
    transpose_cvt<<<dim3(16, 8),  256, 0, stream>>>(w_dkv, wcat1, 1024, 512, 512);
    transpose_cvt<<<dim3(16, 2),  256, 0, stream>>>(w_kr,  wcat1 + 512 * 1024, 1024, 64, 128);
    transpose_cvt<<<dim3(16, 8),  256, 0, stream>>>(w_dq,  wdq_t, 1024, 512, 512);
    transpose_cvt<<<dim3(8, 16),  256, 0, stream>>>(w_uk,  wuk_t, 512, 1024, 1024);
    transpose_cvt<<<dim3(8, 16),  256, 0, stream>>>(w_uv,  wuv_t, 512, 1024, 1024);
    transpose_cvt<<<dim3(8, 16),  256, 0, stream>>>(w_uq,  wcat2, 512, 1024, 1024);
    transpose_cvt<<<dim3(8, 16),  256, 0, stream>>>(w_qr,  wcat2 + 1024 * 512, 512, 1024, 1024);
    transpose_cvt<<<dim3(16, 16), 256, 0, stream>>>(w_fc,  wfc_t, 1024, 1024, 1024);
    pad_bias_kernel<<<2, 256, 0, stream>>>(b_dkv, bcat1, 512, 512);
    pad_bias_kernel<<<1, 128, 0, stream>>>(b_kr, bcat1 + 512, 64, 128);
    pad_bias_kernel<<<4, 256, 0, stream>>>(b_uq, bcat2, 1024, 1024);
    pad_bias_kernel<<<4, 256, 0, stream>>>(b_qr, bcat2 + 1024, 1024, 1024);

    // projection GEMMs (64x128 tiles)
    gemm64<0><<<dim3(5, R / 64),  256, 0, stream>>>(k_bf, wcat1, bcat1, ckkr, R, 640, 1024, 1024, 1024, 640, 1.0f);
    gemm64<0><<<dim3(4, R / 64),  256, 0, stream>>>(q_bf, wdq_t, b_dq, c_q, R, 512, 1024, 1024, 1024, 512, 1.0f);
    gemm64<0><<<dim3(8, R / 64),  256, 0, stream>>>(ckkr, wuk_t, b_uk, ktc, R, 1024, 512, 640, 512, 1024, 1.0f);
    gemm64<2><<<dim3(8, R / 64),  256, 0, stream>>>(ckkr, wuv_t, b_uv, vtc, R, 1024, 512, 640, 512, 1024, 1.0f);
    transpose_f16<<<dim3(16, R / 64), 256, 0, stream>>>(vtc, vtcT, R, 1024);
    gemm64<0><<<dim3(16, R / 64), 256, 0, stream>>>(c_q, wcat2, bcat2, qcat, R, 2048, 512, 512, 512, 2048, QSCALE);

    // RoPE (in-place; qrope at qcat col 1024, krope at ckkr col 512)
    rope_kernel<<<dim3((R * 16 * 32 + 255) / 256), 256, 0, stream>>>(qcat + 1024, R, 16, 2048, S);
    rope_kernel<<<dim3((R * 32 + 255) / 256), 256, 0, stream>>>(ckkr + 512, R, 1, 640, S);

    // attention
    attn_kernel<<<dim3(S / 128, 16, B), 256, 0, stream>>>(qcat, ktc, ckkr + 512, vtcT, attn_out, S, R);

    // output projection (f32 to d_out)
    gemm64<1><<<dim3(8, R / 64), 256, 0, stream>>>(attn_out, wfc_t, b_fc, (float*)d_out, R, 1024, 1024, 1024, 1024, 1024, 1.0f);
}